// Round 3
// baseline (24664.175 us; speedup 1.0000x reference)
//
#include <hip/hip_runtime.h>

typedef unsigned short u16;
typedef __attribute__((ext_vector_type(4))) float f32x4;
typedef __attribute__((ext_vector_type(2))) float f32x2;
typedef __attribute__((ext_vector_type(8))) short short8;

#define B_ 32
#define P_ 196
#define T_ 64
#define V_ 32000

#define AT_LOAD(p)     __hip_atomic_load((p), __ATOMIC_RELAXED, __HIP_MEMORY_SCOPE_AGENT)
#define AT_STORE(p,v)  __hip_atomic_store((p), (v), __ATOMIC_RELAXED, __HIP_MEMORY_SCOPE_AGENT)
#define AT_LOADA(p)    __hip_atomic_load((p), __ATOMIC_ACQUIRE, __HIP_MEMORY_SCOPE_AGENT)
#define AT_STORER(p,v) __hip_atomic_store((p), (v), __ATOMIC_RELEASE, __HIP_MEMORY_SCOPE_AGENT)

__device__ __forceinline__ u16 f2bf(float x){
  unsigned int u = __float_as_uint(x);
  u += 0x7FFFu + ((u >> 16) & 1u);
  return (u16)(u >> 16);
}
__device__ __forceinline__ float bf2f(u16 x){
  return __uint_as_float(((unsigned int)x) << 16);
}
__device__ __forceinline__ float sigf(float x){ return 1.0f/(1.0f + __expf(-x)); }
__device__ __forceinline__ float tanhfast(float x){
  float e = __expf(-2.0f*fabsf(x));
  float t = (1.0f - e)/(1.0f + e);
  return x >= 0.0f ? t : -t;
}

// ---------- setup kernels ----------

__global__ __launch_bounds__(256) void k_cvt_bf16(const float* __restrict__ s,
                                                  u16* __restrict__ d, int n8){
  int i = blockIdx.x*256 + threadIdx.x;
  if (i >= n8) return;
  const f32x4* sp = (const f32x4*)(s + (size_t)i*8);
  f32x4 a = sp[0], b = sp[1];
  short8 v;
#pragma unroll
  for (int j=0;j<4;++j){ v[j] = (short)f2bf(a[j]); v[4+j] = (short)f2bf(b[j]); }
  *(short8*)(d + (size_t)i*8) = v;
}

__global__ __launch_bounds__(256) void k_wencT(const float* __restrict__ W, u16* __restrict__ WT){
  int tid = threadIdx.x;
  int kc = tid & 63, a = blockIdx.x*4 + (tid >> 6);
  short8 v;
#pragma unroll
  for (int j=0;j<8;++j) v[j] = (short)f2bf(W[(kc*8+j)*512 + a]);
  *(short8*)(WT + a*512 + kc*8) = v;
}

__global__ __launch_bounds__(256) void k_mean(const float* __restrict__ enc, float* __restrict__ mean){
  int b = blockIdx.x, tid = threadIdx.x;
  f32x2 acc; acc.x = 0.f; acc.y = 0.f;
  for (int p=0;p<P_;++p){
    f32x2 v = *(const f32x2*)(enc + ((size_t)(b*P_+p))*512 + tid*2);
    acc.x += v.x; acc.y += v.y;
  }
  acc.x *= (1.0f/196.0f); acc.y *= (1.0f/196.0f);
  *(f32x2*)(mean + b*512 + tid*2) = acc;
}

__global__ __launch_bounds__(256) void k_init_state(const float* __restrict__ mean,
    const float* __restrict__ Wh, const float* __restrict__ bh,
    const float* __restrict__ Wc, const float* __restrict__ bc,
    float* __restrict__ h0, float* __restrict__ h1,
    float* __restrict__ c0, float* __restrict__ c1){
  int bid = blockIdx.x;
  int which = bid >> 7, r = (bid >> 2) & 31, jg = bid & 3;
  const float* W = which ? Wc : Wh;
  const float* bb = which ? bc : bh;
  __shared__ float m[512];
  for (int i=threadIdx.x; i<512; i+=256) m[i] = mean[r*512 + i];
  __syncthreads();
  int j = jg*256 + threadIdx.x;
  float acc = bb[j];
  for (int e=0;e<512;++e) acc += m[e]*W[e*1024 + j];
  int l = r >> 4;
  int bb2 = ((r & 15) << 1) | (j >> 9);
  int hh = j & 511;
  float* dst = which ? (l ? c1 : c0) : (l ? h1 : h0);
  dst[bb2*512 + hh] = acc;
}

// fused LSTM weights: W0f[2048][1536] = [Wih0 | Whh0], W1f[2048][1024] = [Wih1 | Whh1]
__global__ __launch_bounds__(256) void k_fuse_w(const float* __restrict__ Wih0,
    const float* __restrict__ Whh0, const float* __restrict__ Wih1,
    const float* __restrict__ Whh1, float* __restrict__ W0f, float* __restrict__ W1f){
  int r = blockIdx.x, tid = threadIdx.x;
  if (r < 2048){
    for (int k=tid; k<1536; k+=256)
      W0f[(size_t)r*1536+k] = (k<1024) ? Wih0[(size_t)r*1024+k] : Whh0[(size_t)r*512 + (k-1024)];
  } else {
    int r1 = r - 2048;
    for (int k=tid; k<1024; k+=256)
      W1f[(size_t)r1*1024+k] = (k<512) ? Wih1[(size_t)r1*512+k] : Whh1[(size_t)r1*512 + (k-512)];
  }
}

// ---------- bf16 GEMM (LDS pad 40 u16): C[M][N] = A[M][512]*Bm[N][512]^T + bias ----------
#define LDAP 40
__global__ __launch_bounds__(256) void k_gemm_bf16(
    const u16* __restrict__ A, const u16* __restrict__ Bm,
    const float* __restrict__ bias, float* __restrict__ C, int N){
  __shared__ __align__(16) u16 As[128*LDAP];
  __shared__ __align__(16) u16 Bs[128*LDAP];
  int tid = threadIdx.x, l = tid & 63, w = tid >> 6;
  int m0 = blockIdx.x * 128, n0 = blockIdx.y * 128;
  int wm = w >> 1, wn = w & 1;
  f32x4 acc[4][4];
#pragma unroll
  for (int a=0;a<4;++a)
#pragma unroll
    for (int b=0;b<4;++b) acc[a][b] = (f32x4)0.0f;
  int srow = tid >> 2, schunk = tid & 3;
  const u16* gA = A + (size_t)(m0 + srow)*512 + schunk*8;
  const u16* gB = Bm + (size_t)(n0 + srow)*512 + schunk*8;
  int lr = l & 15, lk = (l >> 4) * 8;
  for (int k0 = 0; k0 < 512; k0 += 32){
    short8 va0 = *(const short8*)(gA + k0);
    short8 va1 = *(const short8*)(gA + (size_t)64*512 + k0);
    short8 vb0 = *(const short8*)(gB + k0);
    short8 vb1 = *(const short8*)(gB + (size_t)64*512 + k0);
    __syncthreads();
    *(short8*)(As + srow*LDAP + schunk*8) = va0;
    *(short8*)(As + (64+srow)*LDAP + schunk*8) = va1;
    *(short8*)(Bs + srow*LDAP + schunk*8) = vb0;
    *(short8*)(Bs + (64+srow)*LDAP + schunk*8) = vb1;
    __syncthreads();
    short8 af[4], bfv[4];
#pragma unroll
    for (int mt=0; mt<4; ++mt) af[mt]  = *(const short8*)(As + (wm*64 + mt*16 + lr)*LDAP + lk);
#pragma unroll
    for (int nt=0; nt<4; ++nt) bfv[nt] = *(const short8*)(Bs + (wn*64 + nt*16 + lr)*LDAP + lk);
#pragma unroll
    for (int mt=0; mt<4; ++mt)
#pragma unroll
      for (int nt=0; nt<4; ++nt)
        acc[mt][nt] = __builtin_amdgcn_mfma_f32_16x16x32_bf16(af[mt], bfv[nt], acc[mt][nt], 0, 0, 0);
  }
#pragma unroll
  for (int mt=0; mt<4; ++mt){
    int row = m0 + wm*64 + mt*16 + ((l >> 4) << 2);
#pragma unroll
    for (int nt=0; nt<4; ++nt){
      int col = n0 + wn*64 + nt*16 + (l & 15);
      float bv = bias[col];
#pragma unroll
      for (int j=0;j<4;++j)
        C[(size_t)(row + j)*N + col] = acc[mt][nt][j] + bv;
    }
  }
}

// ---------- persistent recurrence kernel ----------

struct RA {
  const float* enc; const int* caps; const float* embW;
  const float* Wdec; const float* bdec; const float* Wfull; const float* bfull;
  const u16* encattBF; const float* W0f; const float* W1f;
  const float* bih0; const float* bhh0; const float* bih1; const float* bhh1;
  float* h0g0; float* h0g1; float* h1g0; float* h1g1;
  float* att2g; float* expg; float* ctxg;
  const float* c0init; const float* c1init;
  u16* h1_all; int* slots; int* go;
};

__device__ __forceinline__ void gbar(int* slots, int* go, int gen){
  __syncthreads();
  if (blockIdx.x == 0){
    int tid = threadIdx.x;
    if (tid > 0 && tid < 256){
      while (AT_LOADA(&slots[tid]) < gen) __builtin_amdgcn_s_sleep(2);
    }
    __syncthreads();
    if (tid == 0) AT_STORER(go, gen);
  } else {
    if (threadIdx.x == 0){
      AT_STORER(&slots[blockIdx.x], gen);
      while (AT_LOADA(go) < gen) __builtin_amdgcn_s_sleep(2);
    }
    __syncthreads();
  }
}

#define XS_S 396

__global__ __launch_bounds__(512, 1) void k_recur(RA a){
  int bid = blockIdx.x, tid = threadIdx.x;
  int lane = tid & 63, wv = tid >> 6;
  __shared__ __align__(16) float xs[32*XS_S];   // 50688 B
  __shared__ float red[2048];                   // 8 KB scratch (union)
  __shared__ float c0s[64], c1s[64];
  __shared__ float SinvS;
  __shared__ int capl[32];

  if (tid < 64){
    int ci = tid >> 5, b = tid & 31, cell = bid*2 + ci;
    c0s[ci*32+b] = a.c0init[b*512 + cell];
    c1s[ci*32+b] = a.c1init[b*512 + cell];
  }
  int ab = bid >> 3, as = bid & 7, c0col = as*64;

  for (int t = 0; t < T_; ++t){
    float* h0_old = (t&1) ? a.h0g1 : a.h0g0;
    float* h0_new = (t&1) ? a.h0g0 : a.h0g1;
    float* h1_old = (t&1) ? a.h1g1 : a.h1g0;
    float* h1_new = (t&1) ? a.h1g0 : a.h1g1;
    int genb = t*5;

    // ---- P1: att2[b][c0col..+64) ----
    {
      float* h1s = red; float* gp = red + 512;
      __syncthreads();
      h1s[tid] = AT_LOAD(&h1_old[ab*512 + tid]);
      __syncthreads();
      int c = tid & 63, ks = tid >> 6;
      float acc = 0.f;
      const float* wp = a.Wdec + (size_t)(ks*64)*512 + c0col + c;
      for (int i=0;i<64;++i) acc = fmaf(h1s[ks*64+i], wp[(size_t)i*512], acc);
      gp[ks*64+c] = acc;
      __syncthreads();
      if (tid < 64){
        float s = a.bdec[c0col+tid];
#pragma unroll
        for (int k=0;k<8;++k) s += gp[k*64+tid];
        AT_STORE(&a.att2g[ab*512 + c0col + tid], s);
      }
    }
    gbar(a.slots, a.go, genb+1);

    // ---- P2: logits -> exp ----
    {
      float* att2s = red;
      att2s[tid] = AT_LOAD(&a.att2g[ab*512 + tid]);
      __syncthreads();
      int base = as*25, cnt = (as<7) ? 25 : 21;
      float bf0 = a.bfull[0];
      for (int i=0;i<4;++i){
        int idx = wv + i*8;
        if (idx < cnt){
          int p = base + idx;
          const u16* ep = a.encattBF + ((size_t)(ab*P_ + p))*512;
          float s = 0.f;
#pragma unroll
          for (int j=0;j<8;++j){
            int k = j*64 + lane;
            s += fmaxf(bf2f(ep[k]) + att2s[k], 0.f) * a.Wfull[k];
          }
#pragma unroll
          for (int o=32;o>=1;o>>=1) s += __shfl_xor(s, o);
          if (lane == 0) AT_STORE(&a.expg[ab*224 + p], __expf(s + bf0));
        }
      }
    }
    gbar(a.slots, a.go, genb+2);

    // ---- P3: softmax-normalize + context cols ----
    {
      float* es = red + 1536; float* gp3 = red + 512;
      if (tid < 224) es[tid] = (tid < P_) ? AT_LOAD(&a.expg[ab*224 + tid]) : 0.f;
      __syncthreads();
      if (wv == 0){
        float v = 0.f;
#pragma unroll
        for (int i=0;i<4;++i){ int p = lane + 64*i; if (p < P_) v += es[p]; }
#pragma unroll
        for (int o=32;o>=1;o>>=1) v += __shfl_xor(v, o);
        if (lane == 0) SinvS = 1.0f / v;
      }
      int c = tid & 63, pk = tid >> 6;
      float acc = 0.f;
      for (int i=0;i<25;++i){
        int p = pk + 8*i;
        if (p < P_) acc = fmaf(es[p], a.enc[((size_t)(ab*P_ + p))*512 + c0col + c], acc);
      }
      gp3[pk*64+c] = acc;
      __syncthreads();
      if (tid < 64){
        float s = 0.f;
#pragma unroll
        for (int k=0;k<8;++k) s += gp3[k*64+tid];
        AT_STORE(&a.ctxg[ab*512 + c0col + tid], s * SinvS);
      }
    }
    gbar(a.slots, a.go, genb+3);

    // ---- P4: LSTM layer 0 (block owns cells bid*2, bid*2+1) ----
    {
      if (tid < 32) capl[tid] = a.caps[tid*T_ + t];
      int bg = tid & 3, rg = (tid >> 2) & 3, ks = tid >> 4;
      float acc[2][8];
#pragma unroll
      for (int r=0;r<2;++r)
#pragma unroll
        for (int b=0;b<8;++b) acc[r][b] = 0.f;
      int row0 = rg*512 + bid*2;
      for (int kc=0; kc<4; ++kc){
        __syncthreads();
        {
          int sb = tid >> 4, seg = tid & 15;
#pragma unroll 4
          for (int j=0;j<24;++j){
            int kl = seg*24 + j, k = kc*384 + kl;
            float v;
            if (k < 512)       v = a.embW[(size_t)capl[sb]*512 + k];
            else if (k < 1024) v = AT_LOAD(&a.ctxg[sb*512 + (k-512)]);
            else               v = AT_LOAD(&h0_old[sb*512 + (k-1024)]);
            xs[sb*XS_S + kl] = v;
          }
        }
        __syncthreads();
#pragma unroll
        for (int kk=0; kk<12; kk+=4){
          int kl = ks*12 + kk, kg = kc*384 + kl;
          f32x4 wA = *(const f32x4*)(a.W0f + (size_t)(row0  )*1536 + kg);
          f32x4 wB = *(const f32x4*)(a.W0f + (size_t)(row0+1)*1536 + kg);
#pragma unroll
          for (int bb=0;bb<8;++bb){
            int b = bg + 4*bb;
            f32x4 xv = *(const f32x4*)(xs + b*XS_S + kl);
            acc[0][bb] += xv.x*wA.x + xv.y*wA.y + xv.z*wA.z + xv.w*wA.w;
            acc[1][bb] += xv.x*wB.x + xv.y*wB.y + xv.z*wB.z + xv.w*wB.w;
          }
        }
      }
      __syncthreads();
#pragma unroll
      for (int rr=0;rr<2;++rr)
#pragma unroll
        for (int bb=0;bb<8;++bb){
          float v = acc[rr][bb];
          v += __shfl_xor(v, 16); v += __shfl_xor(v, 32);
          if ((lane >> 4) == 0) red[wv*256 + (rg*4+bg)*16 + rr*8 + bb] = v;
        }
      __syncthreads();
      if (tid < 64){
        int ci = tid >> 5, b = tid & 31, bg2 = b & 3, bb2 = b >> 2;
        int cell = bid*2 + ci;
        float G[4];
#pragma unroll
        for (int g=0; g<4; ++g){
          float s = a.bih0[g*512+cell] + a.bhh0[g*512+cell];
#pragma unroll
          for (int w8=0; w8<8; ++w8) s += red[w8*256 + (g*4+bg2)*16 + ci*8 + bb2];
          G[g] = s;
        }
        float cp = c0s[ci*32+b];
        float cn = sigf(G[1])*cp + sigf(G[0])*tanhfast(G[2]);
        float hn = sigf(G[3])*tanhfast(cn);
        c0s[ci*32+b] = cn;
        AT_STORE(&h0_new[b*512 + cell], hn);
      }
    }
    gbar(a.slots, a.go, genb+4);

    // ---- P5: LSTM layer 1 ----
    {
      int bg = tid & 3, rg = (tid >> 2) & 3, ks = tid >> 4;
      float acc[2][8];
#pragma unroll
      for (int r=0;r<2;++r)
#pragma unroll
        for (int b=0;b<8;++b) acc[r][b] = 0.f;
      int row0 = rg*512 + bid*2;
      const int kcb[4] = {0, 384, 768, 1024};
      for (int kc=0; kc<3; ++kc){
        int clen = kcb[kc+1] - kcb[kc];
        __syncthreads();
        {
          int sb = tid >> 4, seg = tid & 15, per = clen >> 4;
          for (int j=0;j<per;++j){
            int kl = seg*per + j, k = kcb[kc] + kl;
            float v = (k < 512) ? AT_LOAD(&h0_new[sb*512 + k])
                                : AT_LOAD(&h1_old[sb*512 + (k-512)]);
            xs[sb*XS_S + kl] = v;
          }
        }
        __syncthreads();
        int perk = clen >> 5;
        for (int kk=0; kk<perk; kk+=4){
          int kl = ks*perk + kk, kg = kcb[kc] + kl;
          f32x4 wA = *(const f32x4*)(a.W1f + (size_t)(row0  )*1024 + kg);
          f32x4 wB = *(const f32x4*)(a.W1f + (size_t)(row0+1)*1024 + kg);
#pragma unroll
          for (int bb=0;bb<8;++bb){
            int b = bg + 4*bb;
            f32x4 xv = *(const f32x4*)(xs + b*XS_S + kl);
            acc[0][bb] += xv.x*wA.x + xv.y*wA.y + xv.z*wA.z + xv.w*wA.w;
            acc[1][bb] += xv.x*wB.x + xv.y*wB.y + xv.z*wB.z + xv.w*wB.w;
          }
        }
      }
      __syncthreads();
#pragma unroll
      for (int rr=0;rr<2;++rr)
#pragma unroll
        for (int bb=0;bb<8;++bb){
          float v = acc[rr][bb];
          v += __shfl_xor(v, 16); v += __shfl_xor(v, 32);
          if ((lane >> 4) == 0) red[wv*256 + (rg*4+bg)*16 + rr*8 + bb] = v;
        }
      __syncthreads();
      if (tid < 64){
        int ci = tid >> 5, b = tid & 31, bg2 = b & 3, bb2 = b >> 2;
        int cell = bid*2 + ci;
        float G[4];
#pragma unroll
        for (int g=0; g<4; ++g){
          float s = a.bih1[g*512+cell] + a.bhh1[g*512+cell];
#pragma unroll
          for (int w8=0; w8<8; ++w8) s += red[w8*256 + (g*4+bg2)*16 + ci*8 + bb2];
          G[g] = s;
        }
        float cp = c1s[ci*32+b];
        float cn = sigf(G[1])*cp + sigf(G[0])*tanhfast(G[2]);
        float hn = sigf(G[3])*tanhfast(cn);
        c1s[ci*32+b] = cn;
        AT_STORE(&h1_new[b*512 + cell], hn);
        a.h1_all[((size_t)(b*T_ + t))*512 + cell] = f2bf(hn);
      }
    }
    gbar(a.slots, a.go, genb+5);
  }
}

// ---------- host ----------

extern "C" void kernel_launch(void* const* d_in, const int* in_sizes, int n_in,
                              void* d_out, int out_size, void* d_ws, size_t ws_size,
                              hipStream_t stream){
  const float* enc   = (const float*)d_in[0];
  const int*   caps  = (const int*)d_in[1];
  const float* embW  = (const float*)d_in[2];
  const float* fc_b  = (const float*)d_in[3];
  const float* Wenc  = (const float*)d_in[4];
  const float* benc  = (const float*)d_in[5];
  const float* Wdec  = (const float*)d_in[6];
  const float* bdec  = (const float*)d_in[7];
  const float* Wfull = (const float*)d_in[8];
  const float* bfull = (const float*)d_in[9];
  const float* Wih0  = (const float*)d_in[10];
  const float* Whh0  = (const float*)d_in[11];
  const float* bih0  = (const float*)d_in[12];
  const float* bhh0  = (const float*)d_in[13];
  const float* Wih1  = (const float*)d_in[14];
  const float* Whh1  = (const float*)d_in[15];
  const float* bih1  = (const float*)d_in[16];
  const float* bhh1  = (const float*)d_in[17];
  const float* Winh  = (const float*)d_in[18];
  const float* binh  = (const float*)d_in[19];
  const float* Winc  = (const float*)d_in[20];
  const float* binc  = (const float*)d_in[21];
  float* out = (float*)d_out;

  char* wsp = (char*)d_ws;
  size_t off = 0;
  auto alloc = [&](size_t bytes)->char*{
    char* p = wsp + off;
    off += (bytes + 255) & ~(size_t)255;
    return p;
  };
  u16*   A_enc    = (u16*)  alloc((size_t)6272*512*2);
  u16*   emb_bf   = (u16*)  alloc((size_t)V_*512*2);
  u16*   WencT    = (u16*)  alloc((size_t)512*512*2);
  float* encatt   = (float*)alloc((size_t)6272*512*4);
  u16*   encattBF = (u16*)  alloc((size_t)6272*512*2);
  float* meanb    = (float*)alloc((size_t)32*512*4);
  float* W0f      = (float*)alloc((size_t)2048*1536*4);
  float* W1f      = (float*)alloc((size_t)2048*1024*4);
  float* h0g0     = (float*)alloc(32*512*4);
  float* h0g1     = (float*)alloc(32*512*4);
  float* h1g0     = (float*)alloc(32*512*4);
  float* h1g1     = (float*)alloc(32*512*4);
  float* att2g    = (float*)alloc(32*512*4);
  float* expg     = (float*)alloc(32*224*4);
  float* ctxg     = (float*)alloc(32*512*4);
  float* c0init   = (float*)alloc(32*512*4);
  float* c1init   = (float*)alloc(32*512*4);
  u16*   h1_all   = (u16*)  alloc((size_t)2048*512*2);
  int*   syncA    = (int*)  alloc(257*4);
  if (off > ws_size) return;
  int* slots = syncA; int* go = syncA + 256;

  // setup
  hipMemsetAsync(syncA, 0, 257*4, stream);
  k_cvt_bf16<<<1568, 256, 0, stream>>>(enc, A_enc, 401408);
  k_cvt_bf16<<<8000, 256, 0, stream>>>(embW, emb_bf, 2048000);
  k_wencT   <<<128, 256, 0, stream>>>(Wenc, WencT);
  k_mean    <<<32, 256, 0, stream>>>(enc, meanb);
  k_init_state<<<256, 256, 0, stream>>>(meanb, Winh, binh, Winc, binc,
                                        h0g0, h1g0, c0init, c1init);
  k_fuse_w<<<4096, 256, 0, stream>>>(Wih0, Whh0, Wih1, Whh1, W0f, W1f);
  k_gemm_bf16<<<dim3(49, 4), 256, 0, stream>>>(A_enc, WencT, benc, encatt, 512);
  k_cvt_bf16<<<1568, 256, 0, stream>>>(encatt, encattBF, 401408);

  // persistent recurrence (cooperative: guarantees 256-block co-residency)
  RA ra;
  ra.enc = enc; ra.caps = caps; ra.embW = embW;
  ra.Wdec = Wdec; ra.bdec = bdec; ra.Wfull = Wfull; ra.bfull = bfull;
  ra.encattBF = encattBF; ra.W0f = W0f; ra.W1f = W1f;
  ra.bih0 = bih0; ra.bhh0 = bhh0; ra.bih1 = bih1; ra.bhh1 = bhh1;
  ra.h0g0 = h0g0; ra.h0g1 = h0g1; ra.h1g0 = h1g0; ra.h1g1 = h1g1;
  ra.att2g = att2g; ra.expg = expg; ra.ctxg = ctxg;
  ra.c0init = c0init; ra.c1init = c1init;
  ra.h1_all = h1_all; ra.slots = slots; ra.go = go;
  void* kp[] = { &ra };
  hipLaunchCooperativeKernel((const void*)k_recur, dim3(256), dim3(512), kp, 0, stream);

  // deferred tied-weight projection: out[2048][32000] = h1_all @ emb_W^T + fc_b
  k_gemm_bf16<<<dim3(16, 250), 256, 0, stream>>>(h1_all, emb_bf, fc_b, out, V_);
}

// Round 4
// 5891.340 us; speedup vs baseline: 4.1865x; 4.1865x over previous
//
#include <hip/hip_runtime.h>

typedef unsigned short u16;
typedef __attribute__((ext_vector_type(4))) float f32x4;
typedef __attribute__((ext_vector_type(2))) float f32x2;
typedef __attribute__((ext_vector_type(8))) short short8;

#define B_ 32
#define P_ 196
#define T_ 64
#define V_ 32000

// All cross-block data goes through relaxed agent-scope atomics (coherent at
// MALL on gfx950). NO acquire/release anywhere: ordering is provided by
// __syncthreads() (compiler emits s_waitcnt vmcnt(0) before s_barrier), so by
// the time a block signals its flag, its data stores have reached MALL.
#define AT_LOAD(p)     __hip_atomic_load((p), __ATOMIC_RELAXED, __HIP_MEMORY_SCOPE_AGENT)
#define AT_STORE(p,v)  __hip_atomic_store((p), (v), __ATOMIC_RELAXED, __HIP_MEMORY_SCOPE_AGENT)

__device__ __forceinline__ u16 f2bf(float x){
  unsigned int u = __float_as_uint(x);
  u += 0x7FFFu + ((u >> 16) & 1u);
  return (u16)(u >> 16);
}
__device__ __forceinline__ float bf2f(u16 x){
  return __uint_as_float(((unsigned int)x) << 16);
}
__device__ __forceinline__ float sigf(float x){ return 1.0f/(1.0f + __expf(-x)); }
__device__ __forceinline__ float tanhfast(float x){
  float e = __expf(-2.0f*fabsf(x));
  float t = (1.0f - e)/(1.0f + e);
  return x >= 0.0f ? t : -t;
}

// ---------- setup kernels ----------

__global__ __launch_bounds__(256) void k_cvt_bf16(const float* __restrict__ s,
                                                  u16* __restrict__ d, int n8){
  int i = blockIdx.x*256 + threadIdx.x;
  if (i >= n8) return;
  const f32x4* sp = (const f32x4*)(s + (size_t)i*8);
  f32x4 a = sp[0], b = sp[1];
  short8 v;
#pragma unroll
  for (int j=0;j<4;++j){ v[j] = (short)f2bf(a[j]); v[4+j] = (short)f2bf(b[j]); }
  *(short8*)(d + (size_t)i*8) = v;
}

__global__ __launch_bounds__(256) void k_wencT(const float* __restrict__ W, u16* __restrict__ WT){
  int tid = threadIdx.x;
  int kc = tid & 63, a = blockIdx.x*4 + (tid >> 6);
  short8 v;
#pragma unroll
  for (int j=0;j<8;++j) v[j] = (short)f2bf(W[(kc*8+j)*512 + a]);
  *(short8*)(WT + a*512 + kc*8) = v;
}

__global__ __launch_bounds__(256) void k_mean(const float* __restrict__ enc, float* __restrict__ mean){
  int b = blockIdx.x, tid = threadIdx.x;
  f32x2 acc; acc.x = 0.f; acc.y = 0.f;
  for (int p=0;p<P_;++p){
    f32x2 v = *(const f32x2*)(enc + ((size_t)(b*P_+p))*512 + tid*2);
    acc.x += v.x; acc.y += v.y;
  }
  acc.x *= (1.0f/196.0f); acc.y *= (1.0f/196.0f);
  *(f32x2*)(mean + b*512 + tid*2) = acc;
}

__global__ __launch_bounds__(256) void k_init_state(const float* __restrict__ mean,
    const float* __restrict__ Wh, const float* __restrict__ bh,
    const float* __restrict__ Wc, const float* __restrict__ bc,
    float* __restrict__ h0, float* __restrict__ h1,
    float* __restrict__ c0, float* __restrict__ c1){
  int bid = blockIdx.x;
  int which = bid >> 7, r = (bid >> 2) & 31, jg = bid & 3;
  const float* W = which ? Wc : Wh;
  const float* bb = which ? bc : bh;
  __shared__ float m[512];
  for (int i=threadIdx.x; i<512; i+=256) m[i] = mean[r*512 + i];
  __syncthreads();
  int j = jg*256 + threadIdx.x;
  float acc = bb[j];
  for (int e=0;e<512;++e) acc += m[e]*W[e*1024 + j];
  int l = r >> 4;
  int bb2 = ((r & 15) << 1) | (j >> 9);
  int hh = j & 511;
  float* dst = which ? (l ? c1 : c0) : (l ? h1 : h0);
  dst[bb2*512 + hh] = acc;
}

// fused LSTM weights: W0f[2048][1536] = [Wih0 | Whh0], W1f[2048][1024] = [Wih1 | Whh1]
__global__ __launch_bounds__(256) void k_fuse_w(const float* __restrict__ Wih0,
    const float* __restrict__ Whh0, const float* __restrict__ Wih1,
    const float* __restrict__ Whh1, float* __restrict__ W0f, float* __restrict__ W1f){
  int r = blockIdx.x, tid = threadIdx.x;
  if (r < 2048){
    for (int k=tid; k<1536; k+=256)
      W0f[(size_t)r*1536+k] = (k<1024) ? Wih0[(size_t)r*1024+k] : Whh0[(size_t)r*512 + (k-1024)];
  } else {
    int r1 = r - 2048;
    for (int k=tid; k<1024; k+=256)
      W1f[(size_t)r1*1024+k] = (k<512) ? Wih1[(size_t)r1*512+k] : Whh1[(size_t)r1*512 + (k-512)];
  }
}

// ---------- bf16 GEMM (LDS pad 40 u16): C[M][N] = A[M][512]*Bm[N][512]^T + bias ----------
#define LDAP 40
__global__ __launch_bounds__(256) void k_gemm_bf16(
    const u16* __restrict__ A, const u16* __restrict__ Bm,
    const float* __restrict__ bias, float* __restrict__ C, int N){
  __shared__ __align__(16) u16 As[128*LDAP];
  __shared__ __align__(16) u16 Bs[128*LDAP];
  int tid = threadIdx.x, l = tid & 63, w = tid >> 6;
  int m0 = blockIdx.x * 128, n0 = blockIdx.y * 128;
  int wm = w >> 1, wn = w & 1;
  f32x4 acc[4][4];
#pragma unroll
  for (int a=0;a<4;++a)
#pragma unroll
    for (int b=0;b<4;++b) acc[a][b] = (f32x4)0.0f;
  int srow = tid >> 2, schunk = tid & 3;
  const u16* gA = A + (size_t)(m0 + srow)*512 + schunk*8;
  const u16* gB = Bm + (size_t)(n0 + srow)*512 + schunk*8;
  int lr = l & 15, lk = (l >> 4) * 8;
  for (int k0 = 0; k0 < 512; k0 += 32){
    short8 va0 = *(const short8*)(gA + k0);
    short8 va1 = *(const short8*)(gA + (size_t)64*512 + k0);
    short8 vb0 = *(const short8*)(gB + k0);
    short8 vb1 = *(const short8*)(gB + (size_t)64*512 + k0);
    __syncthreads();
    *(short8*)(As + srow*LDAP + schunk*8) = va0;
    *(short8*)(As + (64+srow)*LDAP + schunk*8) = va1;
    *(short8*)(Bs + srow*LDAP + schunk*8) = vb0;
    *(short8*)(Bs + (64+srow)*LDAP + schunk*8) = vb1;
    __syncthreads();
    short8 af[4], bfv[4];
#pragma unroll
    for (int mt=0; mt<4; ++mt) af[mt]  = *(const short8*)(As + (wm*64 + mt*16 + lr)*LDAP + lk);
#pragma unroll
    for (int nt=0; nt<4; ++nt) bfv[nt] = *(const short8*)(Bs + (wn*64 + nt*16 + lr)*LDAP + lk);
#pragma unroll
    for (int mt=0; mt<4; ++mt)
#pragma unroll
      for (int nt=0; nt<4; ++nt)
        acc[mt][nt] = __builtin_amdgcn_mfma_f32_16x16x32_bf16(af[mt], bfv[nt], acc[mt][nt], 0, 0, 0);
  }
#pragma unroll
  for (int mt=0; mt<4; ++mt){
    int row = m0 + wm*64 + mt*16 + ((l >> 4) << 2);
#pragma unroll
    for (int nt=0; nt<4; ++nt){
      int col = n0 + wn*64 + nt*16 + (l & 15);
      float bv = bias[col];
#pragma unroll
      for (int j=0;j<4;++j)
        C[(size_t)(row + j)*N + col] = acc[mt][nt][j] + bv;
    }
  }
}

// ---------- persistent recurrence kernel ----------

struct RA {
  const float* enc; const int* caps; const float* embW;
  const float* Wdec; const float* bdec; const float* Wfull; const float* bfull;
  const u16* encattBF; const float* W0f; const float* W1f;
  const float* bih0; const float* bhh0; const float* bih1; const float* bhh1;
  float* h0g0; float* h0g1; float* h1g0; float* h1g1;
  float* att2g; float* ctxg;
  const float* c0init; const float* c1init;
  u16* h1_all; int* slots; int* go;
};

// Grid barrier: relaxed-only flags; __syncthreads() provides the vmcnt(0)
// drain so data stores are at MALL before the flag store. Monotone counters.
__device__ __forceinline__ void gbar(int* slots, int* go, int gen){
  __syncthreads();
  if (blockIdx.x == 0){
    int tid = threadIdx.x;
    if (tid >= 1 && tid < 256){
      while (AT_LOAD(&slots[tid]) < gen) __builtin_amdgcn_s_sleep(1);
    }
    __syncthreads();
    if (tid == 0) AT_STORE(go, gen);
  } else {
    if (threadIdx.x == 0){
      AT_STORE(&slots[blockIdx.x], gen);
      while (AT_LOAD(go) < gen) __builtin_amdgcn_s_sleep(1);
    }
    __syncthreads();
  }
}

#define XSS 258  // (2b+k)%32 -> max 2-way LDS aliasing (free), 8B aligned

__global__ __launch_bounds__(512, 1) void k_recur(RA a){
  int bid = blockIdx.x, tid = threadIdx.x;
  int lane = tid & 63, wv = tid >> 6;
  __shared__ __align__(16) float xs[32*XSS];   // 33 KB x-staging
  __shared__ __align__(16) float red[4096];    // 16 KB partials / scratch
  __shared__ float gsum[256];
  __shared__ float c0s[64], c1s[64];
  __shared__ float SinvS;
  __shared__ int capl[32];

  if (tid < 64){
    int ci = tid >> 5, b = tid & 31, cell = bid*2 + ci;
    c0s[ci*32+b] = a.c0init[b*512 + cell];
    c1s[ci*32+b] = a.c1init[b*512 + cell];
  }
  int ab = bid >> 3, as = bid & 7, c0col = as*64;
  int b31 = tid & 31, ksg = tid >> 5;   // b31: batch lane, ksg: k-slice 0..15

  // wave-uniform weight row pointers: rows ri = ci*4+g -> global row g*512+bid*2+ci
  const float* wp0[8]; const float* wp1[8];
#pragma unroll
  for (int ci=0; ci<2; ++ci)
#pragma unroll
    for (int g=0; g<4; ++g){
      wp0[ci*4+g] = a.W0f + (size_t)(g*512 + bid*2 + ci)*1536;
      wp1[ci*4+g] = a.W1f + (size_t)(g*512 + bid*2 + ci)*1024;
    }
  __syncthreads();

  for (int t = 0; t < T_; ++t){
    float* h0_old = (t&1) ? a.h0g1 : a.h0g0;
    float* h0_new = (t&1) ? a.h0g0 : a.h0g1;
    float* h1_old = (t&1) ? a.h1g1 : a.h1g0;
    float* h1_new = (t&1) ? a.h1g0 : a.h1g1;
    int genb = t*4;

    // ---- P1: att2 cols [c0col, c0col+64) for batch ab ----
    {
      float* h1s = red; float* gp = red + 512;
      h1s[tid] = AT_LOAD(&h1_old[ab*512 + tid]);
      __syncthreads();
      int c = tid & 63, ksx = tid >> 6;
      float acc = 0.f;
      const float* wpd = a.Wdec + (size_t)(ksx*64)*512 + c0col + c;
#pragma unroll 8
      for (int i=0;i<64;++i) acc = fmaf(h1s[ksx*64+i], wpd[(size_t)i*512], acc);
      gp[ksx*64+c] = acc;
      __syncthreads();
      if (tid < 64){
        float s = a.bdec[c0col+tid];
#pragma unroll
        for (int k=0;k<8;++k) s += gp[k*64+tid];
        AT_STORE(&a.att2g[ab*512 + c0col + tid], s);
      }
    }
    gbar(a.slots, a.go, genb+1);

    // ---- P23: logits+softmax (redundant per 8-block group) + ctx cols ----
    {
      float* att2s = red; float* gp3 = red + 1024; float* alph = red + 2048;
      att2s[tid] = AT_LOAD(&a.att2g[ab*512 + tid]);
      __syncthreads();
      float a2[8], wf[8];
#pragma unroll
      for (int j=0;j<8;++j){ a2[j] = att2s[lane*8+j]; wf[j] = a.Wfull[lane*8+j]; }
      float bf0 = a.bfull[0];
      int np = (wv < 4) ? 25 : 24;
      for (int i=0;i<np;++i){
        int p = wv + i*8;
        const u16* ep = a.encattBF + ((size_t)(ab*P_ + p))*512 + lane*8;
        short8 ev = *(const short8*)ep;
        float s = 0.f;
#pragma unroll
        for (int j=0;j<8;++j)
          s += fmaxf(bf2f((u16)ev[j]) + a2[j], 0.f) * wf[j];
#pragma unroll
        for (int o=32;o>=1;o>>=1) s += __shfl_xor(s, o);
        if (lane == 0) alph[p] = __expf(s + bf0);
      }
      __syncthreads();
      if (wv == 0){
        float v = 0.f;
#pragma unroll
        for (int i=0;i<4;++i){ int p = lane + 64*i; if (p < P_) v += alph[p]; }
#pragma unroll
        for (int o=32;o>=1;o>>=1) v += __shfl_xor(v, o);
        if (lane == 0) SinvS = 1.0f / v;
      }
      __syncthreads();
      int c = tid & 63, pk = tid >> 6;
      float acc = 0.f;
      for (int i=0;i<25;++i){
        int p = pk + 8*i;
        if (p < P_) acc = fmaf(alph[p], a.enc[((size_t)(ab*P_ + p))*512 + c0col + c], acc);
      }
      gp3[pk*64+c] = acc;
      __syncthreads();
      if (tid < 64){
        float s = 0.f;
#pragma unroll
        for (int k=0;k<8;++k) s += gp3[k*64+tid];
        AT_STORE(&a.ctxg[ab*512 + c0col + tid], s * SinvS);
      }
    }
    gbar(a.slots, a.go, genb+2);

    // ---- P4: LSTM layer 0 (block owns cells bid*2, bid*2+1) ----
    {
      if (tid < 32) capl[tid] = a.caps[tid*T_ + t];
      float acc8[8];
#pragma unroll
      for (int r=0;r<8;++r) acc8[r] = 0.f;
      __syncthreads();
      for (int ch=0; ch<6; ++ch){
        if (ch < 2){
          const float* src = a.embW + (size_t)capl[b31]*512 + ch*256 + ksg*16;
#pragma unroll
          for (int q=0;q<4;++q){
            f32x4 v = *(const f32x4*)(src + q*4);
            f32x2 lo, hi; lo.x=v.x; lo.y=v.y; hi.x=v.z; hi.y=v.w;
            *(f32x2*)&xs[b31*XSS + ksg*16 + q*4]     = lo;
            *(f32x2*)&xs[b31*XSS + ksg*16 + q*4 + 2] = hi;
          }
        } else {
          const float* srcb = (ch < 4) ? (a.ctxg + b31*512 + (ch-2)*256)
                                       : (h0_old + b31*512 + (ch-4)*256);
#pragma unroll
          for (int q=0;q<8;++q){
            int k = ksg*16 + q*2;
            unsigned long long u = __hip_atomic_load(
              (const unsigned long long*)(srcb + k), __ATOMIC_RELAXED, __HIP_MEMORY_SCOPE_AGENT);
            f32x2 v2;
            v2.x = __uint_as_float((unsigned)(u & 0xffffffffu));
            v2.y = __uint_as_float((unsigned)(u >> 32));
            *(f32x2*)&xs[b31*XSS + k] = v2;
          }
        }
        __syncthreads();
#pragma unroll
        for (int q=0;q<4;++q){
          int kl = ksg*16 + q*4;
          f32x2 x0 = *(const f32x2*)&xs[b31*XSS + kl];
          f32x2 x1 = *(const f32x2*)&xs[b31*XSS + kl + 2];
          int kg = ch*256 + kl;
#pragma unroll
          for (int r=0;r<8;++r){
            f32x4 w4 = *(const f32x4*)(wp0[r] + kg);
            acc8[r] += x0.x*w4.x + x0.y*w4.y + x1.x*w4.z + x1.y*w4.w;
          }
        }
        __syncthreads();
      }
#pragma unroll
      for (int r=0;r<8;++r) red[r*512 + ksg*32 + b31] = acc8[r];
      __syncthreads();
      if (tid < 256){
        int r = tid >> 5, bb = tid & 31;
        float s = 0.f;
#pragma unroll
        for (int kq=0;kq<16;++kq) s += red[r*512 + kq*32 + bb];
        gsum[r*32 + bb] = s;
      }
      __syncthreads();
      if (tid < 64){
        int ci = tid >> 5, bb = tid & 31, cell = bid*2 + ci;
        float G[4];
#pragma unroll
        for (int g=0;g<4;++g)
          G[g] = gsum[(ci*4+g)*32 + bb] + a.bih0[g*512+cell] + a.bhh0[g*512+cell];
        float cp = c0s[ci*32+bb];
        float cn = sigf(G[1])*cp + sigf(G[0])*tanhfast(G[2]);
        float hn = sigf(G[3])*tanhfast(cn);
        c0s[ci*32+bb] = cn;
        AT_STORE(&h0_new[bb*512 + cell], hn);
      }
    }
    gbar(a.slots, a.go, genb+3);

    // ---- P5: LSTM layer 1 ----
    {
      float acc8[8];
#pragma unroll
      for (int r=0;r<8;++r) acc8[r] = 0.f;
      for (int ch=0; ch<4; ++ch){
        const float* srcb = (ch < 2) ? (h0_new + b31*512 + ch*256)
                                     : (h1_old + b31*512 + (ch-2)*256);
#pragma unroll
        for (int q=0;q<8;++q){
          int k = ksg*16 + q*2;
          unsigned long long u = __hip_atomic_load(
            (const unsigned long long*)(srcb + k), __ATOMIC_RELAXED, __HIP_MEMORY_SCOPE_AGENT);
          f32x2 v2;
          v2.x = __uint_as_float((unsigned)(u & 0xffffffffu));
          v2.y = __uint_as_float((unsigned)(u >> 32));
          *(f32x2*)&xs[b31*XSS + k] = v2;
        }
        __syncthreads();
#pragma unroll
        for (int q=0;q<4;++q){
          int kl = ksg*16 + q*4;
          f32x2 x0 = *(const f32x2*)&xs[b31*XSS + kl];
          f32x2 x1 = *(const f32x2*)&xs[b31*XSS + kl + 2];
          int kg = ch*256 + kl;
#pragma unroll
          for (int r=0;r<8;++r){
            f32x4 w4 = *(const f32x4*)(wp1[r] + kg);
            acc8[r] += x0.x*w4.x + x0.y*w4.y + x1.x*w4.z + x1.y*w4.w;
          }
        }
        __syncthreads();
      }
#pragma unroll
      for (int r=0;r<8;++r) red[r*512 + ksg*32 + b31] = acc8[r];
      __syncthreads();
      if (tid < 256){
        int r = tid >> 5, bb = tid & 31;
        float s = 0.f;
#pragma unroll
        for (int kq=0;kq<16;++kq) s += red[r*512 + kq*32 + bb];
        gsum[r*32 + bb] = s;
      }
      __syncthreads();
      if (tid < 64){
        int ci = tid >> 5, bb = tid & 31, cell = bid*2 + ci;
        float G[4];
#pragma unroll
        for (int g=0;g<4;++g)
          G[g] = gsum[(ci*4+g)*32 + bb] + a.bih1[g*512+cell] + a.bhh1[g*512+cell];
        float cp = c1s[ci*32+bb];
        float cn = sigf(G[1])*cp + sigf(G[0])*tanhfast(G[2]);
        float hn = sigf(G[3])*tanhfast(cn);
        c1s[ci*32+bb] = cn;
        AT_STORE(&h1_new[bb*512 + cell], hn);
        a.h1_all[((size_t)(bb*T_ + t))*512 + cell] = f2bf(hn);
      }
    }
    gbar(a.slots, a.go, genb+4);
  }
}

// ---------- host ----------

extern "C" void kernel_launch(void* const* d_in, const int* in_sizes, int n_in,
                              void* d_out, int out_size, void* d_ws, size_t ws_size,
                              hipStream_t stream){
  const float* enc   = (const float*)d_in[0];
  const int*   caps  = (const int*)d_in[1];
  const float* embW  = (const float*)d_in[2];
  const float* fc_b  = (const float*)d_in[3];
  const float* Wenc  = (const float*)d_in[4];
  const float* benc  = (const float*)d_in[5];
  const float* Wdec  = (const float*)d_in[6];
  const float* bdec  = (const float*)d_in[7];
  const float* Wfull = (const float*)d_in[8];
  const float* bfull = (const float*)d_in[9];
  const float* Wih0  = (const float*)d_in[10];
  const float* Whh0  = (const float*)d_in[11];
  const float* bih0  = (const float*)d_in[12];
  const float* bhh0  = (const float*)d_in[13];
  const float* Wih1  = (const float*)d_in[14];
  const float* Whh1  = (const float*)d_in[15];
  const float* bih1  = (const float*)d_in[16];
  const float* bhh1  = (const float*)d_in[17];
  const float* Winh  = (const float*)d_in[18];
  const float* binh  = (const float*)d_in[19];
  const float* Winc  = (const float*)d_in[20];
  const float* binc  = (const float*)d_in[21];
  float* out = (float*)d_out;

  char* wsp = (char*)d_ws;
  size_t off = 0;
  auto alloc = [&](size_t bytes)->char*{
    char* p = wsp + off;
    off += (bytes + 255) & ~(size_t)255;
    return p;
  };
  u16*   A_enc    = (u16*)  alloc((size_t)6272*512*2);
  u16*   emb_bf   = (u16*)  alloc((size_t)V_*512*2);
  u16*   WencT    = (u16*)  alloc((size_t)512*512*2);
  float* encatt   = (float*)alloc((size_t)6272*512*4);
  u16*   encattBF = (u16*)  alloc((size_t)6272*512*2);
  float* meanb    = (float*)alloc((size_t)32*512*4);
  float* W0f      = (float*)alloc((size_t)2048*1536*4);
  float* W1f      = (float*)alloc((size_t)2048*1024*4);
  float* h0g0     = (float*)alloc(32*512*4);
  float* h0g1     = (float*)alloc(32*512*4);
  float* h1g0     = (float*)alloc(32*512*4);
  float* h1g1     = (float*)alloc(32*512*4);
  float* att2g    = (float*)alloc(32*512*4);
  float* ctxg     = (float*)alloc(32*512*4);
  float* c0init   = (float*)alloc(32*512*4);
  float* c1init   = (float*)alloc(32*512*4);
  u16*   h1_all   = (u16*)  alloc((size_t)2048*512*2);
  int*   syncA    = (int*)  alloc(257*4);
  if (off > ws_size) return;
  int* slots = syncA; int* go = syncA + 256;

  // setup
  hipMemsetAsync(syncA, 0, 257*4, stream);
  k_cvt_bf16<<<1568, 256, 0, stream>>>(enc, A_enc, 401408);
  k_cvt_bf16<<<8000, 256, 0, stream>>>(embW, emb_bf, 2048000);
  k_wencT   <<<128, 256, 0, stream>>>(Wenc, WencT);
  k_mean    <<<32, 256, 0, stream>>>(enc, meanb);
  k_init_state<<<256, 256, 0, stream>>>(meanb, Winh, binh, Winc, binc,
                                        h0g0, h1g0, c0init, c1init);
  k_fuse_w<<<4096, 256, 0, stream>>>(Wih0, Whh0, Wih1, Whh1, W0f, W1f);
  k_gemm_bf16<<<dim3(49, 4), 256, 0, stream>>>(A_enc, WencT, benc, encatt, 512);
  k_cvt_bf16<<<1568, 256, 0, stream>>>(encatt, encattBF, 401408);

  // persistent recurrence (cooperative: guarantees 256-block co-residency)
  RA ra;
  ra.enc = enc; ra.caps = caps; ra.embW = embW;
  ra.Wdec = Wdec; ra.bdec = bdec; ra.Wfull = Wfull; ra.bfull = bfull;
  ra.encattBF = encattBF; ra.W0f = W0f; ra.W1f = W1f;
  ra.bih0 = bih0; ra.bhh0 = bhh0; ra.bih1 = bih1; ra.bhh1 = bhh1;
  ra.h0g0 = h0g0; ra.h0g1 = h0g1; ra.h1g0 = h1g0; ra.h1g1 = h1g1;
  ra.att2g = att2g; ra.ctxg = ctxg;
  ra.c0init = c0init; ra.c1init = c1init;
  ra.h1_all = h1_all; ra.slots = slots; ra.go = go;
  void* kp[] = { &ra };
  hipLaunchCooperativeKernel((const void*)k_recur, dim3(256), dim3(512), kp, 0, stream);

  // deferred tied-weight projection: out[2048][32000] = h1_all @ emb_W^T + fc_b
  k_gemm_bf16<<<dim3(16, 250), 256, 0, stream>>>(h1_all, emb_bf, fc_b, out, V_);
}